// Round 1
// 137.337 us; speedup vs baseline: 1.1810x; 1.1810x over previous
//
#include <hip/hip_runtime.h>
#include <hip/hip_bf16.h>

#define N_NODES 50000
#define HDIM    256
#define CDIM    32
#define JDIM    96   // C*3 output elements per node
#define NB      64   // nodes per block
#define HP      128  // h-values staged in LDS per pass (2 passes)

// Load element i of a tensor whose dtype is compile-time selected.
template<bool ISBF>
__device__ __forceinline__ float ldu(const void* __restrict__ p, int i) {
    if constexpr (ISBF) return __bfloat162float(((const __hip_bfloat16*)p)[i]);
    else                return ((const float*)p)[i];
}

// out[n, c*3+k] = sum_h W2[h,c] * sech^2(z[n,h]) * W1[k,h]
// Block: 256 threads = 4 waves. Wave w owns channels [8w, 8w+8); lane = node.
// Phase 1 (cooperative): S[h][node] = sech^2(z) in LDS, tanh computed ONCE.
// Phase 2: each thread accumulates 24 outputs; weights come in via SGPR
// (wave-uniform s_load), the only vector-memory op is a stride-1 ds_read_b32.
template<bool ISBF>
__device__ __forceinline__ void run_impl(
    const void* __restrict__ pos,
    const void* __restrict__ W1,
    const void* __restrict__ b1,
    const void* __restrict__ W2,
    void* __restrict__ out,
    float (*S)[NB])
{
    const int tid = threadIdx.x;
    const int w   = tid >> 6;   // wave id = channel group (wave-uniform)
    const int l   = tid & 63;   // lane  = node within block
    const int n   = blockIdx.x * NB + l;
    const bool ok = (n < N_NODES);

    float p0 = 0.f, p1 = 0.f, p2 = 0.f;
    if (ok) {
        p0 = ldu<ISBF>(pos, n * 3 + 0);
        p1 = ldu<ISBF>(pos, n * 3 + 1);
        p2 = ldu<ISBF>(pos, n * 3 + 2);
    }

    float acc[24];
#pragma unroll
    for (int j = 0; j < 24; ++j) acc[j] = 0.0f;

    const int c0 = w * 8;

    for (int pass = 0; pass < 2; ++pass) {
        const int hbase = pass * HP;

        // ---- phase 1: fill S[0..HP)[0..NB) ; each wave covers 32 h-rows ----
        {
            const int h0 = hbase + w * (HP / 4);
#pragma unroll 4
            for (int i = 0; i < HP / 4; ++i) {
                const int h = h0 + i;
                float zb = ldu<ISBF>(b1, h);               // uniform -> SGPR
                float wx = ldu<ISBF>(W1, 0 * HDIM + h);
                float wy = ldu<ISBF>(W1, 1 * HDIM + h);
                float wz = ldu<ISBF>(W1, 2 * HDIM + h);
                float z  = fmaf(p0, wx, fmaf(p1, wy, fmaf(p2, wz, zb)));
                float t  = tanhf(z);
                S[h - hbase][l] = 1.0f - t * t;            // stride-1 write
            }
        }
        __syncthreads();

        // ---- phase 2: accumulate this wave's 8 channels over HP h-values ----
#pragma unroll 4
        for (int i = 0; i < HP; ++i) {
            const int h = hbase + i;
            float s  = S[i][l];                            // ds_read_b32, stride-1
            float wx = ldu<ISBF>(W1, 0 * HDIM + h);        // uniform -> SGPR
            float wy = ldu<ISBF>(W1, 1 * HDIM + h);
            float wz = ldu<ISBF>(W1, 2 * HDIM + h);
            float a0 = s * wx;
            float a1 = s * wy;
            float a2 = s * wz;
#pragma unroll
            for (int q = 0; q < 8; ++q) {
                float w2 = ldu<ISBF>(W2, h * CDIM + c0 + q); // uniform -> SGPR
                acc[q * 3 + 0] = fmaf(a0, w2, acc[q * 3 + 0]);
                acc[q * 3 + 1] = fmaf(a1, w2, acc[q * 3 + 1]);
                acc[q * 3 + 2] = fmaf(a2, w2, acc[q * 3 + 2]);
            }
        }
        if (pass == 0) __syncthreads();   // protect S before pass-1 overwrite
    }

    if (!ok) return;

    if constexpr (ISBF) {
        unsigned int* op = (unsigned int*)((__hip_bfloat16*)out + (size_t)n * JDIM + c0 * 3);
#pragma unroll
        for (int j = 0; j < 24; j += 2) {
            unsigned short lo = __hip_bfloat16_raw(__float2bfloat16(acc[j])).x;
            unsigned short hi = __hip_bfloat16_raw(__float2bfloat16(acc[j + 1])).x;
            op[j >> 1] = ((unsigned int)hi << 16) | lo;
        }
    } else {
        float* op = (float*)out + (size_t)n * JDIM + c0 * 3;
#pragma unroll
        for (int j = 0; j < 24; ++j) op[j] = acc[j];
    }
}

__global__ __launch_bounds__(256, 4) void grad_fused(
    const void* __restrict__ pos,
    const void* __restrict__ W1,
    const void* __restrict__ b1,
    const void* __restrict__ W2,
    void* __restrict__ out)
{
    __shared__ float S[HP][NB];   // 32 KiB -> 4 blocks/CU by LDS

    // ---- runtime dtype detection (wave-uniform, identical across waves) ----
    unsigned short uw = ((const unsigned short*)pos)[threadIdx.x & 63];
    int ef = (uw >> 7) & 0xFF;
    unsigned long long bal = __ballot(ef >= 100 && ef <= 140);
    const bool isbf = __popcll(bal) >= 56;

    if (isbf) run_impl<true >(pos, W1, b1, W2, out, S);
    else      run_impl<false>(pos, W1, b1, W2, out, S);
}

extern "C" void kernel_launch(void* const* d_in, const int* in_sizes, int n_in,
                              void* d_out, int out_size, void* d_ws, size_t ws_size,
                              hipStream_t stream) {
    (void)d_ws; (void)ws_size; (void)in_sizes; (void)n_in; (void)out_size;
    const void* pos = d_in[0];  // [N,3]
    const void* W1  = d_in[1];  // [3,H]
    const void* b1  = d_in[2];  // [H]
    const void* W2  = d_in[3];  // [H,C]

    int block = 256;
    int grid = (N_NODES + NB - 1) / NB;  // 782 blocks
    grad_fused<<<grid, block, 0, stream>>>(pos, W1, b1, W2, d_out);
}

// Round 2
// 121.086 us; speedup vs baseline: 1.3395x; 1.1342x over previous
//
#include <hip/hip_runtime.h>
#include <hip/hip_bf16.h>

#define N_NODES 50000
#define HDIM    256
#define CDIM    32
#define JDIM    96   // C*3 output elements per node
#define NB      64   // nodes per block
#define HP      128  // h-values staged in LDS per pass (2 passes)

// Weight load at a WAVE-UNIFORM index i -> compiler emits scalar s_load.
// bf16 is fetched as whole dwords (sub-dword scalar loads don't exist) and
// unpacked with bit ops; f32 is a direct dword load.
template<bool ISBF>
__device__ __forceinline__ float ldw(const void* __restrict__ p, int i) {
    if constexpr (ISBF) {
        unsigned int d = ((const unsigned int*)p)[i >> 1];
        return __uint_as_float((i & 1) ? (d & 0xffff0000u) : (d << 16));
    } else {
        return ((const float*)p)[i];
    }
}

// Per-lane load (pos only).
template<bool ISBF>
__device__ __forceinline__ float ldv(const void* __restrict__ p, int i) {
    if constexpr (ISBF) return __bfloat162float(((const __hip_bfloat16*)p)[i]);
    else                return ((const float*)p)[i];
}

// out[n, c*3+k] = sum_h W2[h,c] * sech^2(z[n,h]) * W1[k,h]
// Block: 256 threads = 4 waves. Wave w owns channels [8w, 8w+8); lane = node.
// Phase 1: S[h][node] = sech^2(z) in LDS (tanh computed once, branch-free).
// Phase 2: weights arrive via the SCALAR path (s_load, wave-uniform address);
// the only vector-memory op per h is one stride-1 ds_read_b32.
template<bool ISBF>
__device__ __forceinline__ void run_impl(
    const void* __restrict__ pos,
    const void* __restrict__ W1,
    const void* __restrict__ b1,
    const void* __restrict__ W2,
    void* __restrict__ out,
    float (*S)[NB])
{
    const int tid = threadIdx.x;
    // readfirstlane: provably wave-uniform -> all weight addresses scalarize.
    const int w   = __builtin_amdgcn_readfirstlane(tid >> 6);
    const int l   = tid & 63;
    const int n   = blockIdx.x * NB + l;
    const bool ok = (n < N_NODES);

    float p0 = 0.f, p1 = 0.f, p2 = 0.f;
    if (ok) {
        p0 = ldv<ISBF>(pos, n * 3 + 0);
        p1 = ldv<ISBF>(pos, n * 3 + 1);
        p2 = ldv<ISBF>(pos, n * 3 + 2);
    }

    float acc[24];
#pragma unroll
    for (int j = 0; j < 24; ++j) acc[j] = 0.0f;

    const int c0 = w * 8;

    for (int pass = 0; pass < 2; ++pass) {
        const int hbase = pass * HP;

        // ---- phase 1: S[i][l] = sech^2(z[n, hbase+i]); each wave does 32 h ----
        {
            const int h0 = hbase + w * (HP / 4);
#pragma unroll 4
            for (int i = 0; i < HP / 4; ++i) {
                const int h = h0 + i;
                float zb = ldw<ISBF>(b1, h);                 // scalar
                float wx = ldw<ISBF>(W1, 0 * HDIM + h);      // scalar
                float wy = ldw<ISBF>(W1, 1 * HDIM + h);      // scalar
                float wz = ldw<ISBF>(W1, 2 * HDIM + h);      // scalar
                float z  = fmaf(p0, wx, fmaf(p1, wy, fmaf(p2, wz, zb)));
                // sech^2(z) = 4u/(1+u)^2, u = e^{-2|z|} in (0,1] -> no overflow,
                // no branches. u==0 at large |z| gives exactly 0.
                float u   = __expf(-2.0f * fabsf(z));
                float inv = __builtin_amdgcn_rcpf(1.0f + u);
                S[h - hbase][l] = 4.0f * u * inv * inv;      // stride-1 write
            }
        }
        __syncthreads();

        // ---- phase 2: accumulate this wave's 8 channels over HP h-values ----
#pragma unroll 4
        for (int i = 0; i < HP; ++i) {
            const int h = hbase + i;
            float s  = S[i][l];                              // ds_read_b32, stride-1
            float wx = ldw<ISBF>(W1, 0 * HDIM + h);          // scalar
            float wy = ldw<ISBF>(W1, 1 * HDIM + h);          // scalar
            float wz = ldw<ISBF>(W1, 2 * HDIM + h);          // scalar
            float a0 = s * wx;
            float a1 = s * wy;
            float a2 = s * wz;
#pragma unroll
            for (int q = 0; q < 8; ++q) {
                float w2 = ldw<ISBF>(W2, h * CDIM + c0 + q); // scalar (x8 merge)
                acc[q * 3 + 0] = fmaf(a0, w2, acc[q * 3 + 0]);
                acc[q * 3 + 1] = fmaf(a1, w2, acc[q * 3 + 1]);
                acc[q * 3 + 2] = fmaf(a2, w2, acc[q * 3 + 2]);
            }
        }
        if (pass == 0) __syncthreads();   // protect S before pass-1 overwrite
    }

    if (!ok) return;

    if constexpr (ISBF) {
        // 24 bf16 = 12 dwords = 3 x uint4, 16B-aligned (offset = 48B * w).
        unsigned int pk[12];
#pragma unroll
        for (int j = 0; j < 24; j += 2) {
            unsigned short lo = __hip_bfloat16_raw(__float2bfloat16(acc[j])).x;
            unsigned short hi = __hip_bfloat16_raw(__float2bfloat16(acc[j + 1])).x;
            pk[j >> 1] = ((unsigned int)hi << 16) | lo;
        }
        uint4* op = (uint4*)((__hip_bfloat16*)out + (size_t)n * JDIM + c0 * 3);
#pragma unroll
        for (int j = 0; j < 3; ++j)
            op[j] = make_uint4(pk[4 * j], pk[4 * j + 1], pk[4 * j + 2], pk[4 * j + 3]);
    } else {
        float4* op = (float4*)((float*)out + (size_t)n * JDIM + c0 * 3);
#pragma unroll
        for (int j = 0; j < 6; ++j)
            op[j] = make_float4(acc[4 * j], acc[4 * j + 1], acc[4 * j + 2], acc[4 * j + 3]);
    }
}

__global__ __launch_bounds__(256, 4) void grad_fused(
    const void* __restrict__ pos,
    const void* __restrict__ W1,
    const void* __restrict__ b1,
    const void* __restrict__ W2,
    void* __restrict__ out)
{
    __shared__ float S[HP][NB];   // 32 KiB -> up to 5 blocks/CU by LDS

    // ---- runtime dtype detection (wave-uniform, identical across waves) ----
    unsigned short uw = ((const unsigned short*)pos)[threadIdx.x & 63];
    int ef = (uw >> 7) & 0xFF;
    unsigned long long bal = __ballot(ef >= 100 && ef <= 140);
    const bool isbf = __popcll(bal) >= 56;

    if (isbf) run_impl<true >(pos, W1, b1, W2, out, S);
    else      run_impl<false>(pos, W1, b1, W2, out, S);
}

extern "C" void kernel_launch(void* const* d_in, const int* in_sizes, int n_in,
                              void* d_out, int out_size, void* d_ws, size_t ws_size,
                              hipStream_t stream) {
    (void)d_ws; (void)ws_size; (void)in_sizes; (void)n_in; (void)out_size;
    const void* pos = d_in[0];  // [N,3]
    const void* W1  = d_in[1];  // [3,H]
    const void* b1  = d_in[2];  // [H]
    const void* W2  = d_in[3];  // [H,C]

    int block = 256;
    int grid = (N_NODES + NB - 1) / NB;  // 782 blocks
    grad_fused<<<grid, block, 0, stream>>>(pos, W1, b1, W2, d_out);
}